// Round 13
// baseline (526.217 us; speedup 1.0000x reference)
//
#include <hip/hip_runtime.h>

#define T 2048
#define HID 4096
#define NH 32
#define NKV 8
#define HD 128
#define QKV_OUT ((NH + 2*NKV) * HD)   // 6144
#define SCALING 0.08838834764831843f  // 128^-0.5
#define QS2 0.12751744954f            // SCALING * log2(e): QK^T in log2 domain
#define DEFER_THR 10.0f               // defer-max threshold (log2 domain, P<=2^10)
#define ROPE_C 0.20762050593046014f   // log2(10000)/64

typedef __attribute__((ext_vector_type(8))) short bfrag;   // 8 bf16
typedef __attribute__((ext_vector_type(4))) float ffrag;   // 4 f32 acc
typedef __attribute__((ext_vector_type(4))) int  ifrag;    // 16 i8 / 4 i32 acc
typedef __attribute__((ext_vector_type(16))) char c16;

__device__ __forceinline__ short f2bf(float f) {
  unsigned u = __builtin_bit_cast(unsigned, f);
  u += 0x7fffu + ((u >> 16) & 1u);   // RNE
  return (short)(u >> 16);
}

// bf16x2 split: x ~= hi + lo, residual ~2^-17 * |x|
__device__ __forceinline__ void split2(float x, short& hi, short& lo) {
  unsigned u = __builtin_bit_cast(unsigned, x);
  unsigned uh = u + (0x7fffu + ((u >> 16) & 1u));
  hi = (short)(uh >> 16);
  float fh = __builtin_bit_cast(float, uh & 0xffff0000u);
  float r = x - fh;
  unsigned ur = __builtin_bit_cast(unsigned, r);
  ur += 0x7fffu + ((ur >> 16) & 1u);
  lo = (short)(ur >> 16);
}

// async global->LDS, 16 B per lane (LDS dest = wave-uniform base + lane*16)
__device__ __forceinline__ void gload_lds16(const void* g, void* l) {
  __builtin_amdgcn_global_load_lds(
      (const __attribute__((address_space(1))) unsigned int*)g,
      (__attribute__((address_space(3))) unsigned int*)l, 16, 0, 0);
}

// ---- i8 swizzle convention (rule 21): within each 128B window of a row,
// the 16B chunk with logical slot s (0..7) is STORED at slot s ^ (row & 7).
// gemm stages rows linearly via global_load_lds and reads with the same XOR
// -> conflict-free ds_read_b128 (2-way max). All i8 writers apply it.

// ---- fused prep A: blocks [0,T): a_sum + act pack (+rope table for <512);
//      blocks [T, T+6144): w_qkv int32->int8 pack. One launch, fuller GPU.
__global__ __launch_bounds__(256)
void prep_a(const int* __restrict__ qact, float* __restrict__ a_sum,
            char* __restrict__ a_i8, float2* __restrict__ tab,
            const int* __restrict__ wsrc, char* __restrict__ wdst) {
  __shared__ int red[256];
  const int bid = blockIdx.x, tid = threadIdx.x;

  if (bid >= T) {                     // ---- w_qkv conv path ----
    int idx = (bid - T) * 256 + tid;  // n16 = QKV_OUT*HID/16 = 6144 blocks
    const int4* s4 = (const int4*)wsrc + (size_t)idx * 4;
    c16 o;
#pragma unroll
    for (int j = 0; j < 4; j++) {
      int4 v = s4[j];
      o[j*4+0] = (char)v.x; o[j*4+1] = (char)v.y;
      o[j*4+2] = (char)v.z; o[j*4+3] = (char)v.w;
    }
    const int idxp = (idx & ~7) | ((idx & 7) ^ ((idx >> 8) & 7));
    *(c16*)(wdst + (size_t)idxp * 16) = o;
    return;
  }

  const int t = bid;
  if (t < 512) {                      // rope table: T*64 entries
    int idx = t * 256 + tid;
    int p = idx >> 6, j = idx & 63;
    float fr = (float)p * exp2f(-ROPE_C * (float)j);
    float sn, cs; sincosf(fr, &sn, &cs);
    tab[idx] = make_float2(cs, sn);
  }
  const int* row = qact + (size_t)t * HID + tid * 16;
  int s = 0;
  c16 o;
#pragma unroll
  for (int i = 0; i < 4; i++) {
    int4 v = *(const int4*)(row + i * 4);
    s += v.x + v.y + v.z + v.w;
    o[i*4+0] = (char)v.x; o[i*4+1] = (char)v.y;
    o[i*4+2] = (char)v.z; o[i*4+3] = (char)v.w;
  }
  const int chunk = (tid & ~7) | ((tid & 7) ^ (t & 7));   // swizzled slot
  *(c16*)(a_i8 + (size_t)t * HID + chunk * 16) = o;
  red[tid] = s; __syncthreads();
  for (int off = 128; off > 0; off >>= 1) {
    if (tid < off) red[tid] += red[tid + off];
    __syncthreads();
  }
  if (tid == 0) a_sum[t] = (float)red[0];
}

// ---------------- W4A8 GEMM, exact i8 MFMA (R9 state) ---------------------
__global__ __launch_bounds__(256)
void gemm_i8(const char* __restrict__ A, const char* __restrict__ W,
             const float* __restrict__ s_a, const float* __restrict__ asum,
             const float* __restrict__ s_w, const float* __restrict__ z_w,
             float* __restrict__ C, int M, int N, int K) {
  __shared__ __align__(16) char As[2][128 * 128];   // 2x16KB, swizzled content
  __shared__ __align__(16) char Bs[2][128 * 128];   // 2x16KB
  const int tid = threadIdx.x;
  const int lane = tid & 63;
  const int quad = lane >> 4, l15 = lane & 15;
  const int wave = tid >> 6;
  const int wm = (wave >> 1) * 64, wn = (wave & 1) * 64;
  const int bm = blockIdx.y * 128, bn = blockIdx.x * 128;
  const int sr = tid >> 3, sc = (tid & 7) * 16;   // staging: 32 rows/call

  ifrag acc[4][4];
#pragma unroll
  for (int mi = 0; mi < 4; mi++)
#pragma unroll
    for (int ni = 0; ni < 4; ni++)
      acc[mi][ni] = (ifrag){0, 0, 0, 0};

  auto stage = [&](int k0, int b) {
#pragma unroll
    for (int j = 0; j < 4; j++) {
      gload_lds16(A + (size_t)(bm + j * 32 + sr) * K + k0 + sc,
                  &As[b][j * 4096 + tid * 16]);
      gload_lds16(W + (size_t)(bn + j * 32 + sr) * K + k0 + sc,
                  &Bs[b][j * 4096 + tid * 16]);
    }
  };

  // swizzled byte col for k-sub ks: slot (ks*4+quad) ^ (l15&7)
  const int scol0 = ((quad)     ^ (l15 & 7)) * 16;
  const int scol1 = ((4 + quad) ^ (l15 & 7)) * 16;

  // prologue: stage tile 0, drain, sync
  stage(0, 0);
  asm volatile("s_waitcnt vmcnt(0)" ::: "memory");
  __builtin_amdgcn_s_barrier();

  int cur = 0;
  for (int k0 = 0; k0 < K; k0 += 128) {
    if (k0 + 128 < K) stage(k0 + 128, cur ^ 1);   // in flight during compute

#pragma unroll
    for (int ks = 0; ks < 2; ks++) {
      const int scol = ks ? scol1 : scol0;
      ifrag af[4], bfv[4];
#pragma unroll
      for (int mi = 0; mi < 4; mi++)
        af[mi] = *(const ifrag*)&As[cur][(wm + mi * 16 + l15) * 128 + scol];
#pragma unroll
      for (int ni = 0; ni < 4; ni++)
        bfv[ni] = *(const ifrag*)&Bs[cur][(wn + ni * 16 + l15) * 128 + scol];
#pragma unroll
      for (int mi = 0; mi < 4; mi++)
#pragma unroll
        for (int ni = 0; ni < 4; ni++)
          acc[mi][ni] = __builtin_amdgcn_mfma_i32_16x16x64_i8(
              af[mi], bfv[ni], acc[mi][ni], 0, 0, 0);
    }

    // next tile's loads landed during compute; sync and flip
    asm volatile("s_waitcnt vmcnt(0)" ::: "memory");
    __builtin_amdgcn_s_barrier();
    cur ^= 1;
  }

#pragma unroll
  for (int mi = 0; mi < 4; mi++) {
    int row0 = bm + wm + mi * 16 + quad * 4;
#pragma unroll
    for (int r = 0; r < 4; r++) {
      int row = row0 + r;
      float sa = s_a[row], av = asum[row];
#pragma unroll
      for (int ni = 0; ni < 4; ni++) {
        int col = bn + wn + ni * 16 + l15;
        C[(size_t)row * N + col] = (sa * s_w[col]) * ((float)acc[mi][ni][r] - z_w[col] * av);
      }
    }
  }
}

// ---- fused prep B: blocks [0,256): split K/V (rope+split+swizzle);
//      blocks [256, 256+4096): w_o int32->int8 pack.
__global__ __launch_bounds__(256)
void kv_prep(const float* __restrict__ qkv, const int* __restrict__ positions,
             const float2* __restrict__ tab,
             short* __restrict__ Kh, short* __restrict__ Kl,
             short* __restrict__ Vth,
             const int* __restrict__ wsrc, char* __restrict__ wdst) {
  __shared__ __align__(16) short Vh_lds[128 * 72];
  const int bid = blockIdx.x, tid = threadIdx.x;

  if (bid >= 256) {                   // ---- w_o conv path ----
    int idx = (bid - 256) * 256 + tid;  // n16 = HID*HID/16 = 4096 blocks
    const int4* s4 = (const int4*)wsrc + (size_t)idx * 4;
    c16 o;
#pragma unroll
    for (int j = 0; j < 4; j++) {
      int4 v = s4[j];
      o[j*4+0] = (char)v.x; o[j*4+1] = (char)v.y;
      o[j*4+2] = (char)v.z; o[j*4+3] = (char)v.w;
    }
    const int idxp = (idx & ~7) | ((idx & 7) ^ ((idx >> 8) & 7));
    *(c16*)(wdst + (size_t)idxp * 16) = o;
    return;
  }

  const int kvh = bid & 7;
  const int t0 = (bid >> 3) * 64;

  // K: rope + hi/lo split, swizzled slot placement
#pragma unroll
  for (int it = 0; it < 4; it++) {
    int c = tid + 256 * it;
    int key = c >> 4, dc = c & 15;
    const int t = t0 + key;
    const float* kr = qkv + (size_t)t * QKV_OUT
                      + (size_t)NH * HD + (size_t)kvh * HD;
    float4 a = *(const float4*)(kr + dc * 4);
    float4 b = *(const float4*)(kr + dc * 4 + 64);
    float av[4] = {a.x, a.y, a.z, a.w};
    float bv[4] = {b.x, b.y, b.z, b.w};
    const float2* tr = tab + (size_t)positions[t] * 64 + dc * 4;
    short4 ha, la, hb, lb;
    short hh, ll;
#pragma unroll
    for (int jj = 0; jj < 4; jj++) {
      float cs = tr[jj].x, sn = tr[jj].y;
      float x1 = av[jj], x2 = bv[jj];
      float r1 = x1 * cs - x2 * sn;
      float r2 = x2 * cs + x1 * sn;
      split2(r1, hh, ll); ((short*)&ha)[jj] = hh; ((short*)&la)[jj] = ll;
      split2(r2, hh, ll); ((short*)&hb)[jj] = hh; ((short*)&lb)[jj] = ll;
    }
    // logical slots: first write s=dc>>1 (half dc&1), second s=8+(dc>>1)
    const int uu = ((dc >> 1) ^ t) & 7;
    const int h4 = (dc & 1) * 4;
    size_t base = (size_t)kvh * T * HD + (size_t)t * HD;
    *(short4*)(Kh + base + uu * 8 + h4) = ha;
    *(short4*)(Kl + base + uu * 8 + h4) = la;
    *(short4*)(Kh + base + (8 + uu) * 8 + h4) = hb;
    *(short4*)(Kl + base + (8 + uu) * 8 + h4) = lb;
  }
  // V -> bf16 transposed, swizzled key-slot placement within 32-key tiles
#pragma unroll
  for (int i = 0; i < 8; i++) {
    int c = tid + 256 * i;
    int key = c >> 5, dc = c & 31;
    float4 f = *(const float4*)(qkv + (size_t)(t0 + key) * QKV_OUT
                                + (size_t)(NH + NKV) * HD + (size_t)kvh * HD + dc * 4);
    Vh_lds[(dc*4+0)*72 + key] = f2bf(f.x);
    Vh_lds[(dc*4+1)*72 + key] = f2bf(f.y);
    Vh_lds[(dc*4+2)*72 + key] = f2bf(f.z);
    Vh_lds[(dc*4+3)*72 + key] = f2bf(f.w);
  }
  __syncthreads();
#pragma unroll
  for (int i = 0; i < 2; i++) {
    int c = tid + 256 * i;
    int row = c >> 2, cc = c & 3;
    int sd = (row >> 1) & 3;
    size_t o = (size_t)kvh * HD * T + (size_t)row * T + t0 + ((cc ^ sd)) * 8;
    *(bfrag*)(Vth + o) = *(const bfrag*)&Vh_lds[row * 72 + cc * 8];
  }
#pragma unroll
  for (int i = 0; i < 2; i++) {
    int c = tid + 256 * i;
    int row = c >> 2, cc = c & 3;
    int sd = (row >> 1) & 3;
    size_t o = (size_t)kvh * HD * T + (size_t)row * T + t0 + 32 + ((cc ^ sd)) * 8;
    *(bfrag*)(Vth + o) = *(const bfrag*)&Vh_lds[row * 72 + 32 + cc * 8];
  }
}

// ---------------- MFMA flash attention ------------------------------------
// R11 post-mortem: occupancy is hard-capped at 2 blocks/CU; attn is
// LDS-BANDWIDTH-bound (25 b128 reads/wave/tile x 8 waves ~ 2400cy at the
// 85 B/cyc LDS ceiling == the measured 2240cy/tile wall). R12: each wave
// processes TWO adjacent qtiles (32 rows) -- K/V fragments read from LDS
// once feed 2x the MFMAs, halving LDS bytes per unit work. Grid 512 (2/CU),
// balanced pairing g = i<32 ? 63-i : i-32 so co-resident blocks sum to a
// constant 65 tiles. kvh = bid&7 keeps XCD pinning.
__global__ __launch_bounds__(256)
void attn_kernel(const float* __restrict__ qkv, const int* __restrict__ positions,
                 const float2* __restrict__ tab,
                 const short* __restrict__ Kh, const short* __restrict__ Kl,
                 const short* __restrict__ Vth,
                 float* __restrict__ attn) {
  __shared__ __align__(16) short Ksh[2][32 * 128];   // 2x8KB, swizzled
  __shared__ __align__(16) short Ksl[2][32 * 128];   // 2x8KB
  __shared__ __align__(16) short Vsh[2][128 * 32];   // 2x8KB, swizzled
  __shared__ __align__(16) short Psh[4 * 2 * 16 * 40];  // 10KB, per-wave x2 rg

  const int kvh = blockIdx.x & 7;              // == XCD id (round-robin)
  const int i6 = blockIdx.x >> 3;              // 0..63
  const int g  = (i6 < 32) ? (63 - i6) : (i6 - 32);  // balanced CU pairing
  const int nk = g + 1;                        // ktiles (32 keys each)
  const int q00 = g * 32, q01 = g * 32 + 16;   // two row-groups
  const int tid = threadIdx.x;
  const int lane = tid & 63;
  const int wv = tid >> 6;
  const int l15 = lane & 15, quad = lane >> 4;
  const int h = kvh * 4 + wv;
  short* Pw0 = Psh + wv * 1280;
  short* Pw1 = Pw0 + 640;

  const short* KhB = Kh + (size_t)kvh * T * HD;
  const short* KlB = Kl + (size_t)kvh * T * HD;
  const short* VhB = Vth + (size_t)kvh * HD * T;

  // staging source offsets (shorts), loop-invariant; dest is linear lane*16
  const int offK0 = (tid >> 4) * 128 + (tid & 15) * 8;          // rows 0..15
  const int offK1 = offK0 + 16 * 128;                           // rows 16..31
  const int offV0 = (tid >> 2) * T + (tid & 3) * 8;             // dims 0..63
  const int offV1 = offV0 + 64 * T;                             // dims 64..127
  const int wv1k = wv * 1024;                                   // byte chunk

  auto stage = [&](int k0, int b) {
    const short* khs = KhB + (size_t)k0 * HD;
    const short* kls = KlB + (size_t)k0 * HD;
    const short* vs  = VhB + k0;
    gload_lds16(khs + offK0, (char*)&Ksh[b][0] + wv1k);
    gload_lds16(khs + offK1, (char*)&Ksh[b][0] + 4096 + wv1k);
    gload_lds16(kls + offK0, (char*)&Ksl[b][0] + wv1k);
    gload_lds16(kls + offK1, (char*)&Ksl[b][0] + 4096 + wv1k);
    gload_lds16(vs + offV0, (char*)&Vsh[b][0] + wv1k);
    gload_lds16(vs + offV1, (char*)&Vsh[b][0] + 4096 + wv1k);
  };

  // read-side swizzle constants (lane-invariant per kc)
  const int sdv = (l15 >> 1) & 3;                 // V: q' = quad ^ sdv
  const int vq8 = (quad ^ sdv) * 8;
  int uuk[4];                                     // K: u = (s&8)|((s^l15)&7)
#pragma unroll
  for (int kc = 0; kc < 4; kc++) {
    int s = 4 * kc + quad;
    uuk[kc] = ((s & 8) | ((s ^ l15) & 7)) * 8;
  }

  bfrag ones;
#pragma unroll
  for (int j = 0; j < 8; j++) ones[j] = (short)0x3f80;

  // ---- Q load + in-register rope + QS2 prescale + bf16x2 split, x2 rg ----
  bfrag qh0[4], ql0[4], qh1[4], ql1[4];
#pragma unroll
  for (int rg = 0; rg < 2; rg++) {
    const int q0 = rg ? q01 : q00;
    const float* qrow = qkv + (size_t)(q0 + l15) * QKV_OUT + (size_t)h * HD;
    float fvv[4][8];
#pragma unroll
    for (int kc = 0; kc < 4; kc++) {
      float4 f0 = *(const float4*)(qrow + kc * 32 + quad * 8);
      float4 f1 = *(const float4*)(qrow + kc * 32 + quad * 8 + 4);
      fvv[kc][0] = f0.x; fvv[kc][1] = f0.y; fvv[kc][2] = f0.z; fvv[kc][3] = f0.w;
      fvv[kc][4] = f1.x; fvv[kc][5] = f1.y; fvv[kc][6] = f1.z; fvv[kc][7] = f1.w;
    }
    const float2* trw = tab + (size_t)positions[q0 + l15] * 64;
#pragma unroll
    for (int kc = 0; kc < 2; kc++) {
#pragma unroll
      for (int j = 0; j < 8; j++) {
        int d = kc * 32 + quad * 8 + j;        // < 64
        float2 cssn = trw[d];
        float x1 = fvv[kc][j], x2 = fvv[kc + 2][j];
        fvv[kc][j]     = x1 * cssn.x - x2 * cssn.y;
        fvv[kc + 2][j] = x2 * cssn.x + x1 * cssn.y;
      }
    }
#pragma unroll
    for (int kc = 0; kc < 4; kc++)
#pragma unroll
      for (int j = 0; j < 8; j++) {
        short hi, lo; split2(fvv[kc][j] * QS2, hi, lo);
        if (rg) { qh1[kc][j] = hi; ql1[kc][j] = lo; }
        else    { qh0[kc][j] = hi; ql0[kc][j] = lo; }
      }
  }

  ffrag o0[8], o1[8], ol0, ol1;
  ol0 = (ffrag){0.f, 0.f, 0.f, 0.f};
  ol1 = (ffrag){0.f, 0.f, 0.f, 0.f};
#pragma unroll
  for (int n = 0; n < 8; n++) {
    o0[n] = (ffrag){0.f, 0.f, 0.f, 0.f};
    o1[n] = (ffrag){0.f, 0.f, 0.f, 0.f};
  }
  float m0[4] = {-1e30f, -1e30f, -1e30f, -1e30f};
  float m1[4] = {-1e30f, -1e30f, -1e30f, -1e30f};

  // one ktile's full compute for BOTH row-groups; K/V LDS reads shared
  auto compute_tile = [&](int k0, int b, bool maskq) {
    const short* ksh = &Ksh[b][0];
    const short* ksl = &Ksl[b][0];
    const short* vsh = &Vsh[b][0];
    ffrag s0[2], s1[2];
    s0[0] = (ffrag){0.f,0.f,0.f,0.f}; s0[1] = (ffrag){0.f,0.f,0.f,0.f};
    s1[0] = (ffrag){0.f,0.f,0.f,0.f}; s1[1] = (ffrag){0.f,0.f,0.f,0.f};
#pragma unroll
    for (int kc = 0; kc < 4; kc++) {
#pragma unroll
      for (int n = 0; n < 2; n++) {
        const int rb = (n * 16 + l15) * 128 + uuk[kc];
        bfrag bh = *(const bfrag*)&ksh[rb];     // read ONCE,
        bfrag bl = *(const bfrag*)&ksl[rb];     // feed both row-groups
        s0[n] = __builtin_amdgcn_mfma_f32_16x16x32_bf16(qh0[kc], bh, s0[n], 0,0,0);
        s0[n] = __builtin_amdgcn_mfma_f32_16x16x32_bf16(qh0[kc], bl, s0[n], 0,0,0);
        s0[n] = __builtin_amdgcn_mfma_f32_16x16x32_bf16(ql0[kc], bh, s0[n], 0,0,0);
        s1[n] = __builtin_amdgcn_mfma_f32_16x16x32_bf16(qh1[kc], bh, s1[n], 0,0,0);
        s1[n] = __builtin_amdgcn_mfma_f32_16x16x32_bf16(qh1[kc], bl, s1[n], 0,0,0);
        s1[n] = __builtin_amdgcn_mfma_f32_16x16x32_bf16(ql1[kc], bh, s1[n], 0,0,0);
      }
    }
    // ---- online softmax (log2 domain; lane-local defer check), per rg ----
    float sv0[2][4], sv1[2][4], lm0[4], lm1[4];
    bool trig = false;
#pragma unroll
    for (int n = 0; n < 2; n++)
#pragma unroll
      for (int r = 0; r < 4; r++) {
        float v0 = s0[n][r], v1 = s1[n][r];
        if (maskq) {
          int key = k0 + n * 16 + l15;
          int row0r = q00 + quad * 4 + r;
          int row1r = q01 + quad * 4 + r;
          if (key > row0r) v0 = -1e30f;
          if (key > row1r) v1 = -1e30f;
        }
        sv0[n][r] = v0; sv1[n][r] = v1;
      }
#pragma unroll
    for (int r = 0; r < 4; r++) {
      lm0[r] = fmaxf(sv0[0][r], sv0[1][r]);
      lm1[r] = fmaxf(sv1[0][r], sv1[1][r]);
      trig = trig || (lm0[r] > m0[r] + DEFER_THR) || (lm1[r] > m1[r] + DEFER_THR);
    }
    if (__any(trig)) {                       // rare: full reduce + rescale
#pragma unroll
      for (int r = 0; r < 4; r++) {
        float a2 = lm0[r];
        a2 = fmaxf(a2, __shfl_xor(a2, 1));
        a2 = fmaxf(a2, __shfl_xor(a2, 2));
        a2 = fmaxf(a2, __shfl_xor(a2, 4));
        a2 = fmaxf(a2, __shfl_xor(a2, 8));
        float mn = fmaxf(m0[r], a2);
        float a = exp2f(m0[r] - mn);
        m0[r] = mn; ol0[r] *= a;
#pragma unroll
        for (int n = 0; n < 8; n++) o0[n][r] *= a;
        float b2 = lm1[r];
        b2 = fmaxf(b2, __shfl_xor(b2, 1));
        b2 = fmaxf(b2, __shfl_xor(b2, 2));
        b2 = fmaxf(b2, __shfl_xor(b2, 4));
        b2 = fmaxf(b2, __shfl_xor(b2, 8));
        float mn1 = fmaxf(m1[r], b2);
        float a1 = exp2f(m1[r] - mn1);
        m1[r] = mn1; ol1[r] *= a1;
#pragma unroll
        for (int n = 0; n < 8; n++) o1[n][r] *= a1;
      }
    }
#pragma unroll
    for (int n = 0; n < 2; n++)
#pragma unroll
      for (int r = 0; r < 4; r++) {
        Pw0[(quad*4 + r) * 40 + n*16 + l15] = f2bf(exp2f(sv0[n][r] - m0[r]));
        Pw1[(quad*4 + r) * 40 + n*16 + l15] = f2bf(exp2f(sv1[n][r] - m1[r]));
      }
    // ---- PV; l via ones-MFMA; V fragments read ONCE per n ----
    bfrag ph0 = *(const bfrag*)&Pw0[l15 * 40 + quad * 8];
    bfrag ph1 = *(const bfrag*)&Pw1[l15 * 40 + quad * 8];
    ol0 = __builtin_amdgcn_mfma_f32_16x16x32_bf16(ph0, ones, ol0, 0,0,0);
    ol1 = __builtin_amdgcn_mfma_f32_16x16x32_bf16(ph1, ones, ol1, 0,0,0);
#pragma unroll
    for (int n = 0; n < 8; n++) {
      bfrag vh = *(const bfrag*)&vsh[(n * 16 + l15) * 32 + vq8];
      o0[n] = __builtin_amdgcn_mfma_f32_16x16x32_bf16(ph0, vh, o0[n], 0,0,0);
      o1[n] = __builtin_amdgcn_mfma_f32_16x16x32_bf16(ph1, vh, o1[n], 0,0,0);
    }
  };

  // prologue: stage tile 0, drain, sync
  stage(0, 0);
  asm volatile("s_waitcnt vmcnt(0)" ::: "memory");
  __builtin_amdgcn_s_barrier();

  int cur = 0;
  for (int kt = 0; kt < nk - 1; kt++) {        // mask-free main loop
    const int k0 = kt << 5;
    stage(k0 + 32, cur ^ 1);                   // in flight during compute
    compute_tile(k0, cur, false);
    asm volatile("s_waitcnt vmcnt(0)" ::: "memory");
    __builtin_amdgcn_s_barrier();
    cur ^= 1;
  }
  // peeled last ktile (causal mask lives only here)
  compute_tile((nk - 1) << 5, cur, true);

  // ---- normalized output, both row-groups ----
  float inv0[4], inv1[4];
#pragma unroll
  for (int r = 0; r < 4; r++) { inv0[r] = 1.f / ol0[r]; inv1[r] = 1.f / ol1[r]; }
#pragma unroll
  for (int n = 0; n < 8; n++)
#pragma unroll
    for (int r = 0; r < 4; r++) {
      int row0r = q00 + quad * 4 + r;
      int row1r = q01 + quad * 4 + r;
      attn[(size_t)row0r * HID + (size_t)h * HD + n * 16 + l15] = o0[n][r] * inv0[r];
      attn[(size_t)row1r * HID + (size_t)h * HD + n * 16 + l15] = o1[n][r] * inv1[r];
    }
}

// ---------------- dynamic quant with sum (i8 out, swizzled) ---------------
__global__ __launch_bounds__(256)
void quant_kernel(const float* __restrict__ x, char* __restrict__ q2,
                  float* __restrict__ s2, float* __restrict__ sum2) {
  __shared__ float red[256];
  const int t = blockIdx.x, tid = threadIdx.x;
  const float* row = x + (size_t)t * HID;
  float4 v[4];
  float m = 0.f;
#pragma unroll
  for (int i = 0; i < 4; i++) {
    v[i] = *(const float4*)(row + tid * 16 + i * 4);
    m = fmaxf(m, fmaxf(fmaxf(fabsf(v[i].x), fabsf(v[i].y)),
                       fmaxf(fabsf(v[i].z), fabsf(v[i].w))));
  }
  red[tid] = m; __syncthreads();
  for (int off = 128; off > 0; off >>= 1) {
    if (tid < off) red[tid] = fmaxf(red[tid], red[tid + off]);
    __syncthreads();
  }
  float s = fmaxf(red[0], 1e-8f) / 127.f;
  __syncthreads();
  float ssum = 0.f;
  c16 o;
#pragma unroll
  for (int i = 0; i < 4; i++) {
    float q;
    q = fminf(127.f, fmaxf(-127.f, rintf(v[i].x / s))); ssum += q; o[i*4+0] = (char)(int)q;
    q = fminf(127.f, fmaxf(-127.f, rintf(v[i].y / s))); ssum += q; o[i*4+1] = (char)(int)q;
    q = fminf(127.f, fmaxf(-127.f, rintf(v[i].z / s))); ssum += q; o[i*4+2] = (char)(int)q;
    q = fminf(127.f, fmaxf(-127.f, rintf(v[i].w / s))); ssum += q; o[i*4+3] = (char)(int)q;
  }
  const int chunk = (tid & ~7) | ((tid & 7) ^ (t & 7));   // swizzled slot
  *(c16*)(q2 + (size_t)t * HID + chunk * 16) = o;
  red[tid] = ssum; __syncthreads();
  for (int off = 128; off > 0; off >>= 1) {
    if (tid < off) red[tid] += red[tid + off];
    __syncthreads();
  }
  if (tid == 0) { s2[t] = s; sum2[t] = red[0]; }
}

// ---------------- launch ----------------
// Workspace layout (~110 MB): act8 (a_i8/q2) and w8 (wqkv/wo) reused across
// phases; +1MB rope table. 6 launches.
extern "C" void kernel_launch(void* const* d_in, const int* in_sizes, int n_in,
                              void* d_out, int out_size, void* d_ws, size_t ws_size,
                              hipStream_t stream) {
  const int*   positions   = (const int*)d_in[0];
  const int*   q_act       = (const int*)d_in[1];
  const float* act_scale   = (const float*)d_in[2];
  const int*   w_qkv_q     = (const int*)d_in[3];
  const float* w_qkv_scale = (const float*)d_in[4];
  const float* w_qkv_zero  = (const float*)d_in[5];
  const int*   w_o_q       = (const int*)d_in[6];
  const float* w_o_scale   = (const float*)d_in[7];
  const float* w_o_zero    = (const float*)d_in[8];
  float* out = (float*)d_out;

  size_t off = 0;
  auto alloc = [&](size_t bytes) -> void* {
    void* p = (char*)d_ws + off;
    off += (bytes + 255) & ~(size_t)255;
    return p;
  };
  float* qkv   = (float*)alloc((size_t)T * QKV_OUT * 4);         // 50.3 MB
  char*  act8  = (char*)alloc((size_t)T * HID);                  //  8.4 MB (a_i8 / q2)
  char*  w8    = (char*)alloc((size_t)QKV_OUT * HID);            // 25.2 MB (wqkv / wo)
  short* Kh    = (short*)alloc((size_t)NKV * T * HD * 2);        //  8.4 MB
  short* Kl    = (short*)alloc((size_t)NKV * T * HD * 2);        //  8.4 MB
  short* Vth   = (short*)alloc((size_t)NKV * T * HD * 2);        //  8.4 MB
  float* a_sum = (float*)alloc(T * 4);
  float* s2    = (float*)alloc(T * 4);
  float* sum2  = (float*)alloc(T * 4);
  float2* tab  = (float2*)alloc((size_t)T * 64 * 8);             //  1.0 MB
  (void)ws_size;

  prep_a<<<T + QKV_OUT * HID / 16 / 256, 256, 0, stream>>>(
      q_act, a_sum, act8, tab, w_qkv_q, w8);
  gemm_i8<<<dim3(QKV_OUT / 128, T / 128), 256, 0, stream>>>(
      act8, w8, act_scale, a_sum, w_qkv_scale, w_qkv_zero, qkv, T, QKV_OUT, HID);
  kv_prep<<<256 + HID * HID / 16 / 256, 256, 0, stream>>>(
      qkv, positions, tab, Kh, Kl, Vth, w_o_q, w8);   // wqkv dead; reuse w8
  attn_kernel<<<dim3(512), 256, 0, stream>>>(
      qkv, positions, tab, Kh, Kl, Vth, out);
  quant_kernel<<<T, 256, 0, stream>>>(out, act8, s2, sum2);   // a_i8 dead; reuse act8
  gemm_i8<<<dim3(HID / 128, T / 128), 256, 0, stream>>>(
      act8, w8, s2, sum2, w_o_scale, w_o_zero, out, T, HID, HID);
}